// Round 6
// baseline (186.716 us; speedup 1.0000x reference)
//
#include <hip/hip_runtime.h>

// TV-L1 optical flow, B=4, 512x512, 20 iters — temporal blocking (ghost zones)
// R6: packed-fp32 inner math (v_pk_fma_f32 via ext_vector float2), li-only
// cone guards (lj guards were divergent -> free to drop; garbage columns
// never enter the dependency cone), register diet (no lj/gof arrays, no
// u-mirror). 4 launches of k_fused (5 iters each), statics recomputed from x
// via an 82x82 LDS staging pass. LDS: su,spa,spb = 3 x 6400 x 8B = 153.6 KB.
// Halo L=6/R=10 (80x80 region per 64x64 tile). Zero-padding reproduced by
// forcing u=p=0 on out-of-image pixels. Last kernel skips the dead 20th
// p-update and fuses the 3x3 avgpool.

typedef float v2f __attribute__((ext_vector_type(2)));

#define HH 512
#define WW 512
#define BB 4
constexpr int HW   = HH * WW;
constexpr int NTOT = BB * HW;
constexpr float EPS = 1e-8f;

#define T 64          // output tile edge
#define HALO_L 6      // left/top halo
#define REG 80        // region edge = 64 + 6 + 10
#define NPX (REG * REG)   // 6400
#define TPB 1024
#define SLOTS 7       // ceil(6400/1024)
#define NBLK 256      // 4 images x 8x8 tiles
#define XR 82         // x1 staging edge (region + 1-ring for 3x3 gradient)
#define XN (XR * XR)  // 6724 <= 12800 floats available in spa

__device__ __forceinline__ v2f vabs2(v2f a) {
    v2f r; r.x = fabsf(a.x); r.y = fabsf(a.y); return r;
}

// phase: 0 = first (u,p zero-init, write back), 1 = middle (load, write
// back), 2 = last (load, 5 u-phases + 4 p-phases, fused avgpool -> out).
__global__ __launch_bounds__(TPB, 1) void k_fused(
    const float* __restrict__ x,
    v2f* __restrict__ ug, float4* __restrict__ pg,
    const float* __restrict__ lam_p, const float* __restrict__ tau_p,
    const float* __restrict__ theta_p,
    const float* __restrict__ wxp, const float* __restrict__ wyp,
    float* __restrict__ out, int phase)
{
    __shared__ v2f su[NPX];    // (u1,u2)
    __shared__ v2f spa[NPX];   // (p11,p21); doubles as x1 staging buffer
    __shared__ v2f spb[NPX];   // (p12,p22)   -> 153.6 KB total

    const int tid  = threadIdx.x;
    const int blk  = blockIdx.x;
    const int bimg = blk >> 6;
    const int t    = blk & 63;
    const int gi0  = (t >> 3) * T;
    const int gj0  = (t & 7) * T;

    const float lam = lam_p[0], theta = theta_p[0];
    const float r   = tau_p[0] / theta;
    const float tl  = theta * lam;
    const float wx0 = wxp[0], wx1 = wxp[1], wx2 = wxp[2];
    const float wy0 = wyp[0], wy1 = wyp[1], wy2 = wyp[2];

    const int gbase = bimg * HW;
    const float* x0p = x + (size_t)bimg * 2 * HW;
    const float* x1p = x0p + HW;

    int  lis[SLOTS];
    bool inb[SLOTS];
    v2f  rpa[SLOTS], rpb[SLOTS];   // own-pixel p mirrors
    float x0v[SLOTS];

    // ---- pass 1: stage x1 into spa-as-float; per-slot row index + inb;
    //      load state (u via LDS-fill later, p into mirrors) ---------------
    v2f uvin[SLOTS];
    #pragma unroll
    for (int s = 0; s < SLOTS; ++s) {
        int idx = tid + s * TPB;
        if (idx < XN) {
            int li = idx / XR, lj = idx - li * XR;
            int gi = gi0 + li - (HALO_L + 1), gj = gj0 + lj - (HALO_L + 1);
            bool in = ((unsigned)gi < HH) & ((unsigned)gj < WW);
            ((float*)spa)[idx] = in ? x1p[gi * WW + gj] : 0.f;
        }
        if (idx < NPX) {
            int li = idx / REG, lj = idx - li * REG;
            lis[s] = li;
            int gi = gi0 + li - HALO_L, gj = gj0 + lj - HALO_L;
            bool in = ((unsigned)gi < HH) & ((unsigned)gj < WW);
            inb[s] = in;
            int gl = gi * WW + gj;            // valid only when in
            v2f uv = (v2f)(0.f);
            float4 p4 = make_float4(0.f, 0.f, 0.f, 0.f);
            float xv = 0.f;
            if (in) {
                xv = x0p[gl];
                if (phase != 0) {
                    uv = ug[gbase + gl];
                    p4 = pg[gbase + gl];
                }
            }
            x0v[s] = xv;
            uvin[s] = uv;
            v2f pa; pa.x = p4.x; pa.y = p4.y;
            v2f pb; pb.x = p4.z; pb.y = p4.w;
            rpa[s] = pa; rpb[s] = pb;
        }
    }
    __syncthreads();

    // ---- pass 2: statics (g=(gx,gy), rc, th, 1/nm) from staged x1 --------
    v2f  rg[SLOTS];
    float rrc[SLOTS], rth[SLOTS], rnv[SLOTS];
    const float* stg = (const float*)spa;
    #pragma unroll
    for (int s = 0; s < SLOTS; ++s) {
        int idx = tid + s * TPB;
        if (idx < NPX) {
            int li = lis[s], lj = idx - li * REG;
            int sc = (li + 1) * XR + (lj + 1);
            float a00 = stg[sc - XR - 1], a01 = stg[sc - XR], a02 = stg[sc - XR + 1];
            float a10 = stg[sc - 1],      a11 = stg[sc],      a12 = stg[sc + 1];
            float a20 = stg[sc + XR - 1], a21 = stg[sc + XR], a22 = stg[sc + XR + 1];
            const float c6 = 1.f / 6.f;
            float gxv = c6 * (-a00 + a02 - 2.f * a10 + 2.f * a12 - a20 + a22);
            float gyv = c6 * (-a00 - 2.f * a01 - a02 + a20 + 2.f * a21 + a22);
            float nm  = gxv * gxv + gyv * gyv + EPS;
            rg[s].x = gxv; rg[s].y = gyv;
            rrc[s] = a11 - x0v[s];           // zero-padded conv semantics held
            rth[s] = tl * nm;
            rnv[s] = __builtin_amdgcn_rcpf(nm);
        }
    }
    __syncthreads();

    // ---- pass 3: fill LDS state (overwrites staging) ---------------------
    #pragma unroll
    for (int s = 0; s < SLOTS; ++s) {
        int idx = tid + s * TPB;
        if (idx < NPX) {
            su[idx]  = uvin[s];
            spa[idx] = rpa[s];
            spb[idx] = rpb[s];
        }
    }
    __syncthreads();

    // ---- 5 fused iterations ---------------------------------------------
    for (int k = 1; k <= 5; ++k) {
        // u-phase rows [k, REG-2k]; all columns (garbage cols stay outside
        // the dependency cone — see header comment)
        const int lo = k, hi_u = REG - 2 * k;
        #pragma unroll
        for (int s = 0; s < SLOTS; ++s) {
            int idx = tid + s * TPB;
            int li = lis[s];
            if (idx >= NPX || li < lo || li > hi_u) continue;
            v2f uv = su[idx];
            float rho = rrc[s] + rg[s].x * uv.x + rg[s].y * uv.y;
            // th>0 always, so rho==0 takes the inside branch (sign(0)=0 ok)
            float d = (fabsf(rho) < rth[s]) ? rho * rnv[s] : copysignf(tl, rho);
            v2f pal = spa[idx - 1],   par = spa[idx + 1];
            v2f pbt = spb[idx - REG], pbb = spb[idx + REG];
            v2f div = wx0 * pal + wx1 * rpa[s] + wx2 * par
                    + wy0 * pbt + wy1 * rpb[s] + wy2 * pbb;
            v2f nu = uv - d * rg[s] + theta * div;
            if (!inb[s]) nu = (v2f)(0.f);    // zero-padding semantics
            su[idx] = nu;
        }
        __syncthreads();
        if (phase == 2 && k == 5) break;   // 20th p-update is dead code

        // p-phase rows [k, REG-1-2k]
        const int hi_p = REG - 1 - 2 * k;
        #pragma unroll
        for (int s = 0; s < SLOTS; ++s) {
            int idx = tid + s * TPB;
            int li = lis[s];
            if (idx >= NPX || li < lo || li > hi_p) continue;
            v2f uc = su[idx];
            v2f uR = su[idx + 1];
            v2f uB = su[idx + REG];
            v2f gx_ = uR - uc;               // (gu1x, gu2x)
            v2f gy_ = uB - uc;               // (gu1y, gu2y)
            v2f den = 1.f + r * (vabs2(gx_) + vabs2(gy_));   // (d1, d2)
            v2f iden;
            iden.x = __builtin_amdgcn_rcpf(den.x);
            iden.y = __builtin_amdgcn_rcpf(den.y);
            v2f npa = (rpa[s] + r * gx_) * iden;   // (p11, p21)
            v2f npb = (rpb[s] + r * gy_) * iden;   // (p12, p22)
            if (!inb[s]) { npa = (v2f)(0.f); npb = (v2f)(0.f); }
            rpa[s] = npa; rpb[s] = npb;
            spa[idx] = npa; spb[idx] = npb;
        }
        __syncthreads();
    }

    // ---- epilogue --------------------------------------------------------
    if (phase != 2) {
        // write back interior [0,63]^2 (li,lj in [6,69])
        #pragma unroll
        for (int s = 0; s < SLOTS; ++s) {
            int idx = tid + s * TPB;
            if (idx >= NPX) continue;
            int li = lis[s], lj = idx - li * REG;
            if (li < HALO_L || li >= HALO_L + T || lj < HALO_L || lj >= HALO_L + T) continue;
            int gl = (gi0 + li - HALO_L) * WW + (gj0 + lj - HALO_L);
            ug[gbase + gl] = su[idx];
            pg[gbase + gl] = make_float4(rpa[s].x, rpa[s].y, rpb[s].x, rpb[s].y);
        }
    } else {
        // fused avgpool(3,1,1, /9 always); u^5 valid on [-1,64] — exact fit
        const float inv9 = 1.f / 9.f;
        #pragma unroll
        for (int s = 0; s < SLOTS; ++s) {
            int idx = tid + s * TPB;
            if (idx >= NPX) continue;
            int li = lis[s], lj = idx - li * REG;
            if (li < HALO_L || li >= HALO_L + T || lj < HALO_L || lj >= HALO_L + T) continue;
            v2f acc = su[idx - REG - 1] + su[idx - REG] + su[idx - REG + 1]
                    + su[idx - 1]       + su[idx]       + su[idx + 1]
                    + su[idx + REG - 1] + su[idx + REG] + su[idx + REG + 1];
            int gl = (gi0 + li - HALO_L) * WW + (gj0 + lj - HALO_L);
            out[(size_t)bimg * 2 * HW + gl]      = acc.x * inv9;
            out[(size_t)bimg * 2 * HW + HW + gl] = acc.y * inv9;
        }
    }
}

// --------------------------------------------------------------- launch ---
extern "C" void kernel_launch(void* const* d_in, const int* in_sizes, int n_in,
                              void* d_out, int out_size, void* d_ws, size_t ws_size,
                              hipStream_t stream) {
    const float* x     = (const float*)d_in[0];
    const float* lam   = (const float*)d_in[1];
    const float* tau   = (const float*)d_in[2];
    const float* theta = (const float*)d_in[3];
    const float* wx    = (const float*)d_in[4];
    const float* wy    = (const float*)d_in[5];
    float* out = (float*)d_out;

    float*  ws = (float*)d_ws;
    v2f*    ug = (v2f*)ws;                            // 8 MB
    float4* pg = (float4*)(ws + (size_t)2 * NTOT);    // 16 MB

    for (int c = 0; c < 4; ++c) {
        int phase = (c == 0) ? 0 : (c == 3) ? 2 : 1;
        k_fused<<<dim3(NBLK), dim3(TPB), 0, stream>>>(
            x, ug, pg, lam, tau, theta, wx, wy, out, phase);
    }
}